// Round 19
// baseline (734.561 us; speedup 1.0000x reference)
//
#include <hip/hip_runtime.h>
#include <hip/hip_bf16.h>
#include <cstdint>

using bf16x8 = __attribute__((ext_vector_type(8))) short;
using f32x4  = __attribute__((ext_vector_type(4))) float;
using f32x16 = __attribute__((ext_vector_type(16))) float;

typedef const __attribute__((address_space(1))) void* gas_ptr;
typedef __attribute__((address_space(3))) void* lds_ptr;

#define M_ROWS 32768
#define PLANE ((size_t)M_ROWS * 64)

__device__ __forceinline__ short f2bf(float f) {
  unsigned u = __builtin_bit_cast(unsigned, f);
  u += 0x7fffu + ((u >> 16) & 1u);
  return (short)(u >> 16);
}

__device__ __forceinline__ unsigned pack2(float a, float b) {
  unsigned ua = __builtin_bit_cast(unsigned, a);
  ua += 0x7fffu + ((ua >> 16) & 1u);
  unsigned ub = __builtin_bit_cast(unsigned, b);
  ub += 0x7fffu + ((ub >> 16) & 1u);
  return (ua >> 16) | (ub & 0xffff0000u);
}

// ---------- f32 -> bf16 bulk convert (8 elems/thread) ----------
__global__ __launch_bounds__(256) void convert_bf16(const float* __restrict__ src,
                                                    short* __restrict__ dst, int n8) {
  int i = blockIdx.x * 256 + threadIdx.x;
  if (i >= n8) return;
  const float4* s = (const float4*)(src + (size_t)i * 8);
  float4 a = s[0], b = s[1];
  uint4 o;
  o.x = pack2(a.x, a.y); o.y = pack2(a.z, a.w);
  o.z = pack2(b.x, b.y); o.w = pack2(b.z, b.w);
  *(uint4*)(dst + (size_t)i * 8) = o;
}

// ---------- transpose + f32->bf16 convert: dst[C][R] = src[R][C] ----------
__global__ __launch_bounds__(256) void transpose_to_bf16(const float* __restrict__ src,
                                                         short* __restrict__ dst,
                                                         int R, int C) {
  int idx = blockIdx.x * 256 + threadIdx.x;
  if (idx >= R * C) return;
  int c = idx / R;
  int r = idx - c * R;
  dst[(size_t)c * R + r] = f2bf(src[(size_t)r * C + c]);
}

// ---------- 256x256 GEMM, 64 KB depth-2 ring (2 blocks/CU), K=512 ----------
// 16 steps of BK=32, 2 phases each (Mq0/Mq1); slot = step&1 per matrix.
// Stage step t+1 during step t (A at ph0, B at ph1); vmcnt(0) at each step end
// (drain overlapped by the co-resident block). Phase interior identical to the
// proven 8-phase kernel (same FRAG/STG addressing + swizzles).
// MODE 0: A row-major [M][512]; C bf16 plane-split (two-pass LDS bounce).
// MODE 1: A plane-split [8][M][64]; C f32 row-major + bias (direct stores).
template <int MODE>
__device__ __forceinline__ void gemm8p_body(const short* __restrict__ A,
                                            const short* __restrict__ Bt,
                                            void* __restrict__ Cp,
                                            const float* __restrict__ bias,
                                            int Mt, int Nt, int N) {
  constexpr int K = 512;
  __shared__ short lds[32768];        // A: [0,16384) B: [16384,32768)  (64 KB)

  const int tid  = threadIdx.x;
  const int lane = tid & 63;
  const int w    = tid >> 6;          // 0..7
  const int c16  = lane & 15;
  const int g    = lane >> 4;
  const int wm   = w >> 2;            // 0..1
  const int wn   = w & 3;             // 0..3

  const int nwg = gridDim.x;
  const int bid = blockIdx.x;
  const int swz = (bid & 7) * (nwg >> 3) + (bid >> 3);
  const int mtile = swz / Nt;         // A-panel L2 reuse mapping
  const int ntile = swz % Nt;
  const int m0 = mtile * 256;
  const int n0 = ntile * 256;

  const int stg_r = w * 16 + (lane >> 2);
  const int stg_c = ((lane & 3) ^ ((lane >> 3) & 3)) * 8;   // pre-swizzled src chunk
  const short* gA = (MODE == 1)
      ? A + (size_t)(m0 + stg_r) * 64 + stg_c                // plane-relative
      : A + (size_t)(m0 + stg_r) * K + stg_c;
  const short* gB = Bt + (size_t)(n0 + stg_r) * K + stg_c;
  short* const ldsA = lds;
  short* const ldsB = lds + 16384;
  const int stg_d = w * 512;

  const int f_lane = c16 * 32 + ((g ^ ((c16 >> 1) & 3)) * 8);

  f32x4 acc[2][4][4] = {};
  bf16x8 bf[4], af[4];

// stage one 256x32 half-tile (16 KB) of A or B for step st into slot st&1
#define STGA_(st) do {                                                            \
    short* _d = ldsA + ((st) & 1) * 8192 + stg_d;                                 \
    if (MODE == 1) {                                                              \
      const short* _s = gA + (size_t)((st) >> 1) * PLANE + ((st) & 1) * 32;       \
      __builtin_amdgcn_global_load_lds((gas_ptr)_s, (lds_ptr)_d, 16, 0, 0);       \
      __builtin_amdgcn_global_load_lds((gas_ptr)(_s + 128 * 64), (lds_ptr)(_d + 4096), 16, 0, 0); \
    } else {                                                                      \
      const short* _s = gA + ((st) >> 1) * 64 + ((st) & 1) * 32;                  \
      __builtin_amdgcn_global_load_lds((gas_ptr)_s, (lds_ptr)_d, 16, 0, 0);       \
      __builtin_amdgcn_global_load_lds((gas_ptr)(_s + 128 * K), (lds_ptr)(_d + 4096), 16, 0, 0); \
    }                                                                             \
  } while (0)

#define STGB_(st) do {                                                            \
    const short* _s = gB + ((st) >> 1) * 64 + ((st) & 1) * 32;                    \
    short* _d = ldsB + ((st) & 1) * 8192 + stg_d;                                 \
    __builtin_amdgcn_global_load_lds((gas_ptr)_s, (lds_ptr)_d, 16, 0, 0);         \
    __builtin_amdgcn_global_load_lds((gas_ptr)(_s + 128 * K), (lds_ptr)(_d + 4096), 16, 0, 0); \
  } while (0)

#define MFMA_(mq) do {                                                            \
    __builtin_amdgcn_s_setprio(1);                                                \
    _Pragma("unroll")                                                             \
    for (int mf = 0; mf < 4; mf++)                                                \
      _Pragma("unroll")                                                           \
      for (int nf = 0; nf < 4; nf++)                                              \
        acc[mq][mf][nf] = __builtin_amdgcn_mfma_f32_16x16x32_bf16(af[mf], bf[nf], \
                                                      acc[mq][mf][nf], 0, 0, 0);  \
    __builtin_amdgcn_s_setprio(0);                                                \
  } while (0)

// phase Mq0: load B+A frags from slot s, stage A(st); no drain
#define PH0_(s, st) do {                                                          \
    _Pragma("unroll")                                                             \
    for (int nf = 0; nf < 4; nf++)                                                \
      bf[nf] = *(const bf16x8*)&ldsB[(s) * 8192 + (wn * 64 + nf * 16) * 32 + f_lane]; \
    _Pragma("unroll")                                                             \
    for (int mf = 0; mf < 4; mf++)                                                \
      af[mf] = *(const bf16x8*)&ldsA[(s) * 8192 + (wm * 128 + mf * 16) * 32 + f_lane]; \
    STGA_(st);                                                                    \
    asm volatile("" ::: "memory");                                                \
    __builtin_amdgcn_s_barrier();                                                 \
    MFMA_(0);                                                                     \
    asm volatile("" ::: "memory");                                                \
    __builtin_amdgcn_s_barrier();                                                 \
    asm volatile("" ::: "memory");                                                \
  } while (0)

// phase Mq1: A frags (row +64), stage B(st); vmcnt(0) publishes step st
#define PH1_(s, st) do {                                                          \
    _Pragma("unroll")                                                             \
    for (int mf = 0; mf < 4; mf++)                                                \
      af[mf] = *(const bf16x8*)&ldsA[(s) * 8192 + (wm * 128 + 64 + mf * 16) * 32 + f_lane]; \
    STGB_(st);                                                                    \
    asm volatile("" ::: "memory");                                                \
    __builtin_amdgcn_s_barrier();                                                 \
    MFMA_(1);                                                                     \
    asm volatile("s_waitcnt vmcnt(0)" ::: "memory");                              \
    asm volatile("" ::: "memory");                                                \
    __builtin_amdgcn_s_barrier();                                                 \
    asm volatile("" ::: "memory");                                                \
  } while (0)

  // prologue: stage step 0 (A+B), drain, barrier
  STGA_(0); STGB_(0);
  asm volatile("s_waitcnt vmcnt(0)" ::: "memory");
  __builtin_amdgcn_s_barrier();
  asm volatile("" ::: "memory");

  for (int jj = 0; jj < 8; jj++) {
    const int te = 2 * jj;                       // even step, slot 0
    const int to = te + 1;                       // odd step, slot 1
    const int sn = (to + 1 < 16) ? to + 1 : 15;  // clamp: idempotent restage
    PH0_(0, to);
    PH1_(0, to);
    PH0_(1, sn);
    PH1_(1, sn);
  }
#undef PH0_
#undef PH1_
#undef MFMA_
#undef STGA_
#undef STGB_

  // final drain before LDS reuse / wave end (round-12 race fix)
  asm volatile("s_waitcnt vmcnt(0)" ::: "memory");
  __builtin_amdgcn_s_barrier();

  if (MODE == 0) {
    // ---- epilogue: two-pass bounce (each pass = one mq half, 64 KB) ----
    #pragma unroll
    for (int p = 0; p < 2; p++) {
      if (p) __syncthreads();   // pass-0 reads done before pass-1 writes
      #pragma unroll
      for (int mf = 0; mf < 4; mf++)
        #pragma unroll
        for (int nf = 0; nf < 4; nf++) {
          const int lr  = wm * 64 + mf * 16 + g * 4;   // 0..127
          const int col = wn * 64 + nf * 16 + c16;
          #pragma unroll
          for (int r = 0; r < 4; r++)
            lds[(lr + r) * 256 + col] = f2bf(acc[p][mf][nf][r]);
        }
      __syncthreads();
      // fully-coalesced plane stores: 4 col-groups x 128 rows x 128 B
      #pragma unroll
      for (int cg = 0; cg < 4; cg++) {
        const int colbase = n0 + cg * 64;
        const int plane = (colbase >> 9) * 8 + ((colbase >> 6) & 7);
        short* op = (short*)Cp + (size_t)plane * PLANE;
        #pragma unroll
        for (int it = 0; it < 2; it++) {
          const int lr  = it * 64 + (tid >> 3);
          const int sc8 = (tid & 7) * 8;
          const int grow = m0 + (lr >> 6) * 128 + p * 64 + (lr & 63);
          *(uint4*)(op + (size_t)grow * 64 + sc8) =
              *(const uint4*)&lds[lr * 256 + cg * 64 + sc8];
        }
      }
    }
  } else {
    #pragma unroll
    for (int mq = 0; mq < 2; mq++) {
      #pragma unroll
      for (int mf = 0; mf < 4; mf++) {
        #pragma unroll
        for (int nf = 0; nf < 4; nf++) {
          const int row = m0 + wm * 128 + mq * 64 + mf * 16 + g * 4;
          const int col = n0 + wn * 64 + nf * 16 + c16;
          float* C = (float*)Cp;
          const float bb = bias ? bias[col] : 0.f;
          #pragma unroll
          for (int r = 0; r < 4; r++)
            C[(size_t)(row + r) * N + col] = acc[mq][mf][nf][r] + bb;
        }
      }
    }
  }
}

__global__ __launch_bounds__(512, 4) void gemm8p_qkv(const short* __restrict__ A,
                                                     const short* __restrict__ Bt,
                                                     void* __restrict__ Cp,
                                                     int Mt, int Nt, int N) {
  gemm8p_body<0>(A, Bt, Cp, nullptr, Mt, Nt, N);
}
__global__ __launch_bounds__(512, 4) void gemm8p_out(const short* __restrict__ A,
                                                     const short* __restrict__ Bt,
                                                     void* __restrict__ Cp,
                                                     const float* __restrict__ bias,
                                                     int Mt, int Nt, int N) {
  gemm8p_body<1>(A, Bt, Cp, bias, Mt, Nt, N);
}

// ---------- attention: 1 block per (b, h, fr); n_sp=256, dh=64 ----------
// (unchanged from round 18 — verified)
__global__ __launch_bounds__(512, 2) void attn_kernel(const short* __restrict__ qkv,
                                                      short* __restrict__ attn_out) {
  __shared__ short Kl[256 * 64];   // K rows (XOR-slot); later O bounce
  __shared__ short Vr[256 * 64];   // V rows (XOR-slot), then in-place VT [64][256]

  const int tid    = threadIdx.x;
  const int lane   = tid & 63;
  const int w      = tid >> 6;      // 0..7
  const int lane31 = lane & 31;
  const int hi     = lane >> 5;

  const int bid = blockIdx.x;
  const int fr  = bid & 31;
  const int h   = (bid >> 5) & 7;
  const int bb  = bid >> 8;
  const size_t rowbase = (size_t)bb * 8192 + (size_t)fr * 256;
  const short* qp = qkv + (size_t)(0 + h) * PLANE + rowbase * 64;
  const short* kp = qkv + (size_t)(8 + h) * PLANE + rowbase * 64;
  const short* vp = qkv + (size_t)(16 + h) * PLANE + rowbase * 64;

  #pragma unroll
  for (int j = 0; j < 4; j++) {
    const int g  = j * 512 + tid;
    const int r  = g >> 3;
    const int sl = g & 7;
    const int off = r * 128 + ((sl ^ (r & 7)) << 4);
    uint4 kc = *(const uint4*)(kp + (size_t)g * 8);
    *(uint4*)((char*)Kl + off) = kc;
    uint4 vc = *(const uint4*)(vp + (size_t)g * 8);
    *(uint4*)((char*)Vr + off) = vc;
  }
  __syncthreads();

  {
    const int p   = tid & 127;
    const int grp = tid >> 7;
    const int r0 = 2 * p, r1 = 2 * p + 1;
    bf16x8 ta[2], tb[2];
    #pragma unroll
    for (int i = 0; i < 2; i++) {
      const int cb = grp * 32 + i * 16;
      ta[i] = *(const bf16x8*)((const char*)Vr + r0 * 128 + (cb ^ ((r0 & 7) << 4)));
      tb[i] = *(const bf16x8*)((const char*)Vr + r1 * 128 + (cb ^ ((r1 & 7) << 4)));
    }
    __syncthreads();
    #pragma unroll
    for (int i = 0; i < 2; i++) {
      #pragma unroll
      for (int k = 0; k < 8; k++) {
        const int d = grp * 16 + i * 8 + k;
        unsigned pk = ((unsigned)(unsigned short)ta[i][k]) |
                      (((unsigned)(unsigned short)tb[i][k]) << 16);
        *(unsigned*)((char*)Vr + d * 512 + ((4 * p) ^ ((d & 7) << 4))) = pk;
      }
    }
  }
  __syncthreads();

  const int swl = (lane31 & 7) << 4;
  const int q0  = w * 32;
  unsigned pko[16];

  {
    const short* qrow = qp + (size_t)(q0 + lane31) * 64;
    bf16x8 qf[4];
    #pragma unroll
    for (int ds = 0; ds < 4; ds++)
      qf[ds] = *(const bf16x8*)(qrow + ds * 16 + 8 * hi);

    f32x16 o0 = {}, o1 = {};
    float m = 0.f, l = 0.f;

    #pragma unroll
    for (int j = 0; j < 4; j++) {
      f32x16 sA = {}, sB = {};
      __builtin_amdgcn_s_setprio(1);
      #pragma unroll
      for (int ds = 0; ds < 4; ds++) {
        bf16x8 kfA = *(const bf16x8*)((const char*)Kl + (j * 64 + lane31) * 128 +
                                      ((ds * 32 + 16 * hi) ^ swl));
        sA = __builtin_amdgcn_mfma_f32_32x32x16_bf16(kfA, qf[ds], sA, 0, 0, 0);
        bf16x8 kfB = *(const bf16x8*)((const char*)Kl + (j * 64 + 32 + lane31) * 128 +
                                      ((ds * 32 + 16 * hi) ^ swl));
        sB = __builtin_amdgcn_mfma_f32_32x32x16_bf16(kfB, qf[ds], sB, 0, 0, 0);
      }
      __builtin_amdgcn_s_setprio(0);

      float tm[16];
      #pragma unroll
      for (int r = 0; r < 16; r++) tm[r] = fmaxf(sA[r], sB[r]);
      #pragma unroll
      for (int st = 8; st > 0; st >>= 1)
        #pragma unroll
        for (int r = 0; r < 8; r++)
          if (r < st) tm[r] = fmaxf(tm[r], tm[r + st]);
      float bm = fmaxf(tm[0], __shfl_xor(tm[0], 32));

      if (j == 0) {
        m = bm;
      } else if (!__all((bm - m) <= 64.f)) {
        const float mnew = fmaxf(m, bm);
        const float corr = __expf((m - mnew) * 0.125f);
        #pragma unroll
        for (int r = 0; r < 16; r++) { o0[r] *= corr; o1[r] *= corr; }
        l *= corr;
        m = mnew;
      }

      float ts[16];
      #pragma unroll
      for (int r = 0; r < 16; r++) {
        sA[r] = __expf((sA[r] - m) * 0.125f);
        sB[r] = __expf((sB[r] - m) * 0.125f);
        ts[r] = sA[r] + sB[r];
      }
      #pragma unroll
      for (int st = 8; st > 0; st >>= 1)
        #pragma unroll
        for (int r = 0; r < 8; r++)
          if (r < st) ts[r] += ts[r + st];
      l += ts[0] + __shfl_xor(ts[0], 32);

#define PVBLK(SV, rb, mm) do {                                                     \
        unsigned u0 = pack2(SV[(rb) + 0], SV[(rb) + 1]);                           \
        unsigned u1 = pack2(SV[(rb) + 2], SV[(rb) + 3]);                           \
        unsigned u2 = pack2(SV[(rb) + 4], SV[(rb) + 5]);                           \
        unsigned u3 = pack2(SV[(rb) + 6], SV[(rb) + 7]);                           \
        int s0 = hi ? (int)u0 : (int)u2;                                           \
        int s1 = hi ? (int)u1 : (int)u3;                                           \
        int r0 = __shfl_xor(s0, 32);                                               \
        int r1 = __shfl_xor(s1, 32);                                               \
        int4 paw;                                                                  \
        paw.x = hi ? r0 : (int)u0;                                                 \
        paw.y = hi ? r1 : (int)u1;                                                 \
        paw.z = hi ? (int)u2 : r0;                                                 \
        paw.w = hi ? (int)u3 : r1;                                                 \
        bf16x8 pa = __builtin_bit_cast(bf16x8, paw);                               \
        bf16x8 v0f = *(const bf16x8*)((const char*)Vr + (size_t)lane31 * 512 +     \
                                      (((mm) * 32 + 16 * hi) ^ swl));              \
        bf16x8 v1f = *(const bf16x8*)((const char*)Vr + (size_t)(32 + lane31) * 512 + \
                                      (((mm) * 32 + 16 * hi) ^ swl));              \
        o0 = __builtin_amdgcn_mfma_f32_32x32x16_bf16(v0f, pa, o0, 0, 0, 0);        \
        o1 = __builtin_amdgcn_mfma_f32_32x32x16_bf16(v1f, pa, o1, 0, 0, 0);        \
      } while (0)

      PVBLK(sA, 0, j * 4 + 0);
      PVBLK(sA, 8, j * 4 + 1);
      PVBLK(sB, 0, j * 4 + 2);
      PVBLK(sB, 8, j * 4 + 3);
#undef PVBLK
    }

    const float inv = 1.0f / l;
    #pragma unroll
    for (int r = 0; r < 16; r++) { o0[r] *= inv; o1[r] *= inv; }
    #pragma unroll
    for (int g2 = 0; g2 < 4; g2++) {
      pko[2 * g2 + 0] = pack2(o0[4 * g2 + 0], o0[4 * g2 + 1]);
      pko[2 * g2 + 1] = pack2(o0[4 * g2 + 2], o0[4 * g2 + 3]);
      pko[8 + 2 * g2 + 0] = pack2(o1[4 * g2 + 0], o1[4 * g2 + 1]);
      pko[8 + 2 * g2 + 1] = pack2(o1[4 * g2 + 2], o1[4 * g2 + 3]);
    }
  }

  __syncthreads();
  {
    const int row = q0 + lane31;
    const int rx  = (row & 7) << 4;
    #pragma unroll
    for (int g2 = 0; g2 < 4; g2++) {
      uint2 a, b;
      a.x = pko[2 * g2 + 0]; a.y = pko[2 * g2 + 1];
      b.x = pko[8 + 2 * g2 + 0]; b.y = pko[8 + 2 * g2 + 1];
      *(uint2*)((char*)Kl + row * 128 + ((16 * g2 + 8 * hi) ^ rx))      = a;
      *(uint2*)((char*)Kl + row * 128 + ((64 + 16 * g2 + 8 * hi) ^ rx)) = b;
    }
  }
  __syncthreads();
  short* op = attn_out + (size_t)h * PLANE + rowbase * 64;
  #pragma unroll
  for (int j = 0; j < 4; j++) {
    const int row = j * 64 + (tid >> 3);
    const int sl  = tid & 7;
    uint4 v = *(const uint4*)((const char*)Kl + row * 128 + ((sl << 4) ^ ((row & 7) << 4)));
    *(uint4*)(op + (size_t)row * 64 + sl * 8) = v;
  }
}

extern "C" void kernel_launch(void* const* d_in, const int* in_sizes, int n_in,
                              void* d_out, int out_size, void* d_ws, size_t ws_size,
                              hipStream_t stream) {
  const float* x     = (const float*)d_in[0];
  const float* w_qkv = (const float*)d_in[1];
  const float* w_out = (const float*)d_in[2];
  const float* b_out = (const float*)d_in[3];
  float* out = (float*)d_out;

  const int M = M_ROWS, DIM = 512, NQKV = 1536;

  short* wqkvT = (short*)d_ws;
  short* woutT = wqkvT + (size_t)NQKV * DIM;
  short* qkvb  = woutT + (size_t)DIM * DIM;   // 24 planes [32768][64]
  short* attnb = qkvb + (size_t)M * NQKV;     // 8 planes [32768][64]
  short* xbf   = attnb;  // aliased: xbf dead before attn writes

  transpose_to_bf16<<<(DIM * NQKV + 255) / 256, 256, 0, stream>>>(w_qkv, wqkvT, DIM, NQKV);
  transpose_to_bf16<<<(DIM * DIM + 255) / 256, 256, 0, stream>>>(w_out, woutT, DIM, DIM);
  convert_bf16<<<(M * DIM / 8 + 255) / 256, 256, 0, stream>>>(x, xbf, M * DIM / 8);

  gemm8p_qkv<<<(M / 256) * (NQKV / 256), 512, 0, stream>>>(xbf, wqkvT, qkvb,
                                                           M / 256, NQKV / 256, NQKV);

  attn_kernel<<<1024, 512, 0, stream>>>(qkvb, attnb);

  gemm8p_out<<<(M / 256) * (DIM / 256), 512, 0, stream>>>(attnb, woutT, out, b_out,
                                                          M / 256, DIM / 256, DIM);
}

// Round 20
// 161.811 us; speedup vs baseline: 4.5396x; 4.5396x over previous
//
#include <hip/hip_runtime.h>
#include <hip/hip_bf16.h>
#include <cstdint>

using bf16x8 = __attribute__((ext_vector_type(8))) short;
using f32x4  = __attribute__((ext_vector_type(4))) float;
using f32x16 = __attribute__((ext_vector_type(16))) float;

typedef const __attribute__((address_space(1))) void* gas_ptr;
typedef __attribute__((address_space(3))) void* lds_ptr;

#define M_ROWS 32768
#define PLANE ((size_t)M_ROWS * 64)

__device__ __forceinline__ short f2bf(float f) {
  unsigned u = __builtin_bit_cast(unsigned, f);
  u += 0x7fffu + ((u >> 16) & 1u);
  return (short)(u >> 16);
}

__device__ __forceinline__ unsigned pack2(float a, float b) {
  unsigned ua = __builtin_bit_cast(unsigned, a);
  ua += 0x7fffu + ((ua >> 16) & 1u);
  unsigned ub = __builtin_bit_cast(unsigned, b);
  ub += 0x7fffu + ((ub >> 16) & 1u);
  return (ua >> 16) | (ub & 0xffff0000u);
}

// ---------- f32 -> bf16 bulk convert (8 elems/thread) ----------
__global__ __launch_bounds__(256) void convert_bf16(const float* __restrict__ src,
                                                    short* __restrict__ dst, int n8) {
  int i = blockIdx.x * 256 + threadIdx.x;
  if (i >= n8) return;
  const float4* s = (const float4*)(src + (size_t)i * 8);
  float4 a = s[0], b = s[1];
  uint4 o;
  o.x = pack2(a.x, a.y); o.y = pack2(a.z, a.w);
  o.z = pack2(b.x, b.y); o.w = pack2(b.z, b.w);
  *(uint4*)(dst + (size_t)i * 8) = o;
}

// ---------- transpose + f32->bf16 convert: dst[C][R] = src[R][C] ----------
__global__ __launch_bounds__(256) void transpose_to_bf16(const float* __restrict__ src,
                                                         short* __restrict__ dst,
                                                         int R, int C) {
  int idx = blockIdx.x * 256 + threadIdx.x;
  if (idx >= R * C) return;
  int c = idx / R;
  int r = idx - c * R;
  dst[(size_t)c * R + r] = f2bf(src[(size_t)r * C + c]);
}

// ---------- 256x256 GEMM, 64 KB depth-2 ring (2 blocks/CU), K=512 ----------
// 16 steps of BK=32, 2 phases each (Mq0/Mq1); slot = step&1 per matrix.
// Stage step t+1 during step t (A at ph0, B at ph1); vmcnt(0) at each step end
// (drain overlapped by the co-resident block). launch_bounds (512,2): VGPR cap
// 256 (round-19 lesson: (512,4) forced 64 VGPR -> catastrophic spill).
// MODE 0: A row-major [M][512]; C bf16 plane-split (two-pass LDS bounce).
// MODE 1: A plane-split [8][M][64]; C f32 row-major + bias (direct stores).
template <int MODE>
__device__ __forceinline__ void gemm8p_body(const short* __restrict__ A,
                                            const short* __restrict__ Bt,
                                            void* __restrict__ Cp,
                                            const float* __restrict__ bias,
                                            int Mt, int Nt, int N) {
  constexpr int K = 512;
  __shared__ short lds[32768];        // A: [0,16384) B: [16384,32768)  (64 KB)

  const int tid  = threadIdx.x;
  const int lane = tid & 63;
  const int w    = tid >> 6;          // 0..7
  const int c16  = lane & 15;
  const int g    = lane >> 4;
  const int wm   = w >> 2;            // 0..1
  const int wn   = w & 3;             // 0..3

  const int nwg = gridDim.x;
  const int bid = blockIdx.x;
  const int swz = (bid & 7) * (nwg >> 3) + (bid >> 3);
  const int mtile = swz / Nt;         // A-panel L2 reuse mapping
  const int ntile = swz % Nt;
  const int m0 = mtile * 256;
  const int n0 = ntile * 256;

  const int stg_r = w * 16 + (lane >> 2);
  const int stg_c = ((lane & 3) ^ ((lane >> 3) & 3)) * 8;   // pre-swizzled src chunk
  const short* gA = (MODE == 1)
      ? A + (size_t)(m0 + stg_r) * 64 + stg_c                // plane-relative
      : A + (size_t)(m0 + stg_r) * K + stg_c;
  const short* gB = Bt + (size_t)(n0 + stg_r) * K + stg_c;
  short* const ldsA = lds;
  short* const ldsB = lds + 16384;
  const int stg_d = w * 512;

  const int f_lane = c16 * 32 + ((g ^ ((c16 >> 1) & 3)) * 8);

  f32x4 acc[2][4][4] = {};
  bf16x8 bf[4], af[4];

// stage one 256x32 half-tile (16 KB) of A or B for step st into slot st&1
#define STGA_(st) do {                                                            \
    short* _d = ldsA + ((st) & 1) * 8192 + stg_d;                                 \
    if (MODE == 1) {                                                              \
      const short* _s = gA + (size_t)((st) >> 1) * PLANE + ((st) & 1) * 32;       \
      __builtin_amdgcn_global_load_lds((gas_ptr)_s, (lds_ptr)_d, 16, 0, 0);       \
      __builtin_amdgcn_global_load_lds((gas_ptr)(_s + 128 * 64), (lds_ptr)(_d + 4096), 16, 0, 0); \
    } else {                                                                      \
      const short* _s = gA + ((st) >> 1) * 64 + ((st) & 1) * 32;                  \
      __builtin_amdgcn_global_load_lds((gas_ptr)_s, (lds_ptr)_d, 16, 0, 0);       \
      __builtin_amdgcn_global_load_lds((gas_ptr)(_s + 128 * K), (lds_ptr)(_d + 4096), 16, 0, 0); \
    }                                                                             \
  } while (0)

#define STGB_(st) do {                                                            \
    const short* _s = gB + ((st) >> 1) * 64 + ((st) & 1) * 32;                    \
    short* _d = ldsB + ((st) & 1) * 8192 + stg_d;                                 \
    __builtin_amdgcn_global_load_lds((gas_ptr)_s, (lds_ptr)_d, 16, 0, 0);         \
    __builtin_amdgcn_global_load_lds((gas_ptr)(_s + 128 * K), (lds_ptr)(_d + 4096), 16, 0, 0); \
  } while (0)

#define MFMA_(mq) do {                                                            \
    __builtin_amdgcn_s_setprio(1);                                                \
    _Pragma("unroll")                                                             \
    for (int mf = 0; mf < 4; mf++)                                                \
      _Pragma("unroll")                                                           \
      for (int nf = 0; nf < 4; nf++)                                              \
        acc[mq][mf][nf] = __builtin_amdgcn_mfma_f32_16x16x32_bf16(af[mf], bf[nf], \
                                                      acc[mq][mf][nf], 0, 0, 0);  \
    __builtin_amdgcn_s_setprio(0);                                                \
  } while (0)

// phase Mq0: load B+A frags from slot s, stage A(st); no drain
#define PH0_(s, st) do {                                                          \
    _Pragma("unroll")                                                             \
    for (int nf = 0; nf < 4; nf++)                                                \
      bf[nf] = *(const bf16x8*)&ldsB[(s) * 8192 + (wn * 64 + nf * 16) * 32 + f_lane]; \
    _Pragma("unroll")                                                             \
    for (int mf = 0; mf < 4; mf++)                                                \
      af[mf] = *(const bf16x8*)&ldsA[(s) * 8192 + (wm * 128 + mf * 16) * 32 + f_lane]; \
    STGA_(st);                                                                    \
    asm volatile("" ::: "memory");                                                \
    __builtin_amdgcn_s_barrier();                                                 \
    MFMA_(0);                                                                     \
    asm volatile("" ::: "memory");                                                \
    __builtin_amdgcn_s_barrier();                                                 \
    asm volatile("" ::: "memory");                                                \
  } while (0)

// phase Mq1: A frags (row +64), stage B(st); vmcnt(0) publishes step st
#define PH1_(s, st) do {                                                          \
    _Pragma("unroll")                                                             \
    for (int mf = 0; mf < 4; mf++)                                                \
      af[mf] = *(const bf16x8*)&ldsA[(s) * 8192 + (wm * 128 + 64 + mf * 16) * 32 + f_lane]; \
    STGB_(st);                                                                    \
    asm volatile("" ::: "memory");                                                \
    __builtin_amdgcn_s_barrier();                                                 \
    MFMA_(1);                                                                     \
    asm volatile("s_waitcnt vmcnt(0)" ::: "memory");                              \
    asm volatile("" ::: "memory");                                                \
    __builtin_amdgcn_s_barrier();                                                 \
    asm volatile("" ::: "memory");                                                \
  } while (0)

  // prologue: stage step 0 (A+B), drain, barrier
  STGA_(0); STGB_(0);
  asm volatile("s_waitcnt vmcnt(0)" ::: "memory");
  __builtin_amdgcn_s_barrier();
  asm volatile("" ::: "memory");

  for (int jj = 0; jj < 8; jj++) {
    const int te = 2 * jj;                       // even step, slot 0
    const int to = te + 1;                       // odd step, slot 1
    const int sn = (to + 1 < 16) ? to + 1 : 15;  // clamp: idempotent restage
    PH0_(0, to);
    PH1_(0, to);
    PH0_(1, sn);
    PH1_(1, sn);
  }
#undef PH0_
#undef PH1_
#undef MFMA_
#undef STGA_
#undef STGB_

  // final drain before LDS reuse / wave end (round-12 race fix)
  asm volatile("s_waitcnt vmcnt(0)" ::: "memory");
  __builtin_amdgcn_s_barrier();

  if (MODE == 0) {
    // ---- epilogue: two-pass bounce (each pass = one mq half, 64 KB) ----
    #pragma unroll
    for (int p = 0; p < 2; p++) {
      if (p) __syncthreads();   // pass-0 reads done before pass-1 writes
      #pragma unroll
      for (int mf = 0; mf < 4; mf++)
        #pragma unroll
        for (int nf = 0; nf < 4; nf++) {
          const int lr  = wm * 64 + mf * 16 + g * 4;   // 0..127
          const int col = wn * 64 + nf * 16 + c16;
          #pragma unroll
          for (int r = 0; r < 4; r++)
            lds[(lr + r) * 256 + col] = f2bf(acc[p][mf][nf][r]);
        }
      __syncthreads();
      // fully-coalesced plane stores: 4 col-groups x 128 rows x 128 B
      #pragma unroll
      for (int cg = 0; cg < 4; cg++) {
        const int colbase = n0 + cg * 64;
        const int plane = (colbase >> 9) * 8 + ((colbase >> 6) & 7);
        short* op = (short*)Cp + (size_t)plane * PLANE;
        #pragma unroll
        for (int it = 0; it < 2; it++) {
          const int lr  = it * 64 + (tid >> 3);
          const int sc8 = (tid & 7) * 8;
          const int grow = m0 + (lr >> 6) * 128 + p * 64 + (lr & 63);
          *(uint4*)(op + (size_t)grow * 64 + sc8) =
              *(const uint4*)&lds[lr * 256 + cg * 64 + sc8];
        }
      }
    }
  } else {
    #pragma unroll
    for (int mq = 0; mq < 2; mq++) {
      #pragma unroll
      for (int mf = 0; mf < 4; mf++) {
        #pragma unroll
        for (int nf = 0; nf < 4; nf++) {
          const int row = m0 + wm * 128 + mq * 64 + mf * 16 + g * 4;
          const int col = n0 + wn * 64 + nf * 16 + c16;
          float* C = (float*)Cp;
          const float bb = bias ? bias[col] : 0.f;
          #pragma unroll
          for (int r = 0; r < 4; r++)
            C[(size_t)(row + r) * N + col] = acc[mq][mf][nf][r] + bb;
        }
      }
    }
  }
}

__global__ __launch_bounds__(512, 2) void gemm8p_qkv(const short* __restrict__ A,
                                                     const short* __restrict__ Bt,
                                                     void* __restrict__ Cp,
                                                     int Mt, int Nt, int N) {
  gemm8p_body<0>(A, Bt, Cp, nullptr, Mt, Nt, N);
}
__global__ __launch_bounds__(512, 2) void gemm8p_out(const short* __restrict__ A,
                                                     const short* __restrict__ Bt,
                                                     void* __restrict__ Cp,
                                                     const float* __restrict__ bias,
                                                     int Mt, int Nt, int N) {
  gemm8p_body<1>(A, Bt, Cp, bias, Mt, Nt, N);
}

// ---------- attention: 1 block per (b, h, fr); n_sp=256, dh=64 ----------
// (unchanged from round 18 — verified)
__global__ __launch_bounds__(512, 2) void attn_kernel(const short* __restrict__ qkv,
                                                      short* __restrict__ attn_out) {
  __shared__ short Kl[256 * 64];   // K rows (XOR-slot); later O bounce
  __shared__ short Vr[256 * 64];   // V rows (XOR-slot), then in-place VT [64][256]

  const int tid    = threadIdx.x;
  const int lane   = tid & 63;
  const int w      = tid >> 6;      // 0..7
  const int lane31 = lane & 31;
  const int hi     = lane >> 5;

  const int bid = blockIdx.x;
  const int fr  = bid & 31;
  const int h   = (bid >> 5) & 7;
  const int bb  = bid >> 8;
  const size_t rowbase = (size_t)bb * 8192 + (size_t)fr * 256;
  const short* qp = qkv + (size_t)(0 + h) * PLANE + rowbase * 64;
  const short* kp = qkv + (size_t)(8 + h) * PLANE + rowbase * 64;
  const short* vp = qkv + (size_t)(16 + h) * PLANE + rowbase * 64;

  #pragma unroll
  for (int j = 0; j < 4; j++) {
    const int g  = j * 512 + tid;
    const int r  = g >> 3;
    const int sl = g & 7;
    const int off = r * 128 + ((sl ^ (r & 7)) << 4);
    uint4 kc = *(const uint4*)(kp + (size_t)g * 8);
    *(uint4*)((char*)Kl + off) = kc;
    uint4 vc = *(const uint4*)(vp + (size_t)g * 8);
    *(uint4*)((char*)Vr + off) = vc;
  }
  __syncthreads();

  {
    const int p   = tid & 127;
    const int grp = tid >> 7;
    const int r0 = 2 * p, r1 = 2 * p + 1;
    bf16x8 ta[2], tb[2];
    #pragma unroll
    for (int i = 0; i < 2; i++) {
      const int cb = grp * 32 + i * 16;
      ta[i] = *(const bf16x8*)((const char*)Vr + r0 * 128 + (cb ^ ((r0 & 7) << 4)));
      tb[i] = *(const bf16x8*)((const char*)Vr + r1 * 128 + (cb ^ ((r1 & 7) << 4)));
    }
    __syncthreads();
    #pragma unroll
    for (int i = 0; i < 2; i++) {
      #pragma unroll
      for (int k = 0; k < 8; k++) {
        const int d = grp * 16 + i * 8 + k;
        unsigned pk = ((unsigned)(unsigned short)ta[i][k]) |
                      (((unsigned)(unsigned short)tb[i][k]) << 16);
        *(unsigned*)((char*)Vr + d * 512 + ((4 * p) ^ ((d & 7) << 4))) = pk;
      }
    }
  }
  __syncthreads();

  const int swl = (lane31 & 7) << 4;
  const int q0  = w * 32;
  unsigned pko[16];

  {
    const short* qrow = qp + (size_t)(q0 + lane31) * 64;
    bf16x8 qf[4];
    #pragma unroll
    for (int ds = 0; ds < 4; ds++)
      qf[ds] = *(const bf16x8*)(qrow + ds * 16 + 8 * hi);

    f32x16 o0 = {}, o1 = {};
    float m = 0.f, l = 0.f;

    #pragma unroll
    for (int j = 0; j < 4; j++) {
      f32x16 sA = {}, sB = {};
      __builtin_amdgcn_s_setprio(1);
      #pragma unroll
      for (int ds = 0; ds < 4; ds++) {
        bf16x8 kfA = *(const bf16x8*)((const char*)Kl + (j * 64 + lane31) * 128 +
                                      ((ds * 32 + 16 * hi) ^ swl));
        sA = __builtin_amdgcn_mfma_f32_32x32x16_bf16(kfA, qf[ds], sA, 0, 0, 0);
        bf16x8 kfB = *(const bf16x8*)((const char*)Kl + (j * 64 + 32 + lane31) * 128 +
                                      ((ds * 32 + 16 * hi) ^ swl));
        sB = __builtin_amdgcn_mfma_f32_32x32x16_bf16(kfB, qf[ds], sB, 0, 0, 0);
      }
      __builtin_amdgcn_s_setprio(0);

      float tm[16];
      #pragma unroll
      for (int r = 0; r < 16; r++) tm[r] = fmaxf(sA[r], sB[r]);
      #pragma unroll
      for (int st = 8; st > 0; st >>= 1)
        #pragma unroll
        for (int r = 0; r < 8; r++)
          if (r < st) tm[r] = fmaxf(tm[r], tm[r + st]);
      float bm = fmaxf(tm[0], __shfl_xor(tm[0], 32));

      if (j == 0) {
        m = bm;
      } else if (!__all((bm - m) <= 64.f)) {
        const float mnew = fmaxf(m, bm);
        const float corr = __expf((m - mnew) * 0.125f);
        #pragma unroll
        for (int r = 0; r < 16; r++) { o0[r] *= corr; o1[r] *= corr; }
        l *= corr;
        m = mnew;
      }

      float ts[16];
      #pragma unroll
      for (int r = 0; r < 16; r++) {
        sA[r] = __expf((sA[r] - m) * 0.125f);
        sB[r] = __expf((sB[r] - m) * 0.125f);
        ts[r] = sA[r] + sB[r];
      }
      #pragma unroll
      for (int st = 8; st > 0; st >>= 1)
        #pragma unroll
        for (int r = 0; r < 8; r++)
          if (r < st) ts[r] += ts[r + st];
      l += ts[0] + __shfl_xor(ts[0], 32);

#define PVBLK(SV, rb, mm) do {                                                     \
        unsigned u0 = pack2(SV[(rb) + 0], SV[(rb) + 1]);                           \
        unsigned u1 = pack2(SV[(rb) + 2], SV[(rb) + 3]);                           \
        unsigned u2 = pack2(SV[(rb) + 4], SV[(rb) + 5]);                           \
        unsigned u3 = pack2(SV[(rb) + 6], SV[(rb) + 7]);                           \
        int s0 = hi ? (int)u0 : (int)u2;                                           \
        int s1 = hi ? (int)u1 : (int)u3;                                           \
        int r0 = __shfl_xor(s0, 32);                                               \
        int r1 = __shfl_xor(s1, 32);                                               \
        int4 paw;                                                                  \
        paw.x = hi ? r0 : (int)u0;                                                 \
        paw.y = hi ? r1 : (int)u1;                                                 \
        paw.z = hi ? (int)u2 : r0;                                                 \
        paw.w = hi ? (int)u3 : r1;                                                 \
        bf16x8 pa = __builtin_bit_cast(bf16x8, paw);                               \
        bf16x8 v0f = *(const bf16x8*)((const char*)Vr + (size_t)lane31 * 512 +     \
                                      (((mm) * 32 + 16 * hi) ^ swl));              \
        bf16x8 v1f = *(const bf16x8*)((const char*)Vr + (size_t)(32 + lane31) * 512 + \
                                      (((mm) * 32 + 16 * hi) ^ swl));              \
        o0 = __builtin_amdgcn_mfma_f32_32x32x16_bf16(v0f, pa, o0, 0, 0, 0);        \
        o1 = __builtin_amdgcn_mfma_f32_32x32x16_bf16(v1f, pa, o1, 0, 0, 0);        \
      } while (0)

      PVBLK(sA, 0, j * 4 + 0);
      PVBLK(sA, 8, j * 4 + 1);
      PVBLK(sB, 0, j * 4 + 2);
      PVBLK(sB, 8, j * 4 + 3);
#undef PVBLK
    }

    const float inv = 1.0f / l;
    #pragma unroll
    for (int r = 0; r < 16; r++) { o0[r] *= inv; o1[r] *= inv; }
    #pragma unroll
    for (int g2 = 0; g2 < 4; g2++) {
      pko[2 * g2 + 0] = pack2(o0[4 * g2 + 0], o0[4 * g2 + 1]);
      pko[2 * g2 + 1] = pack2(o0[4 * g2 + 2], o0[4 * g2 + 3]);
      pko[8 + 2 * g2 + 0] = pack2(o1[4 * g2 + 0], o1[4 * g2 + 1]);
      pko[8 + 2 * g2 + 1] = pack2(o1[4 * g2 + 2], o1[4 * g2 + 3]);
    }
  }

  __syncthreads();
  {
    const int row = q0 + lane31;
    const int rx  = (row & 7) << 4;
    #pragma unroll
    for (int g2 = 0; g2 < 4; g2++) {
      uint2 a, b;
      a.x = pko[2 * g2 + 0]; a.y = pko[2 * g2 + 1];
      b.x = pko[8 + 2 * g2 + 0]; b.y = pko[8 + 2 * g2 + 1];
      *(uint2*)((char*)Kl + row * 128 + ((16 * g2 + 8 * hi) ^ rx))      = a;
      *(uint2*)((char*)Kl + row * 128 + ((64 + 16 * g2 + 8 * hi) ^ rx)) = b;
    }
  }
  __syncthreads();
  short* op = attn_out + (size_t)h * PLANE + rowbase * 64;
  #pragma unroll
  for (int j = 0; j < 4; j++) {
    const int row = j * 64 + (tid >> 3);
    const int sl  = tid & 7;
    uint4 v = *(const uint4*)((const char*)Kl + row * 128 + ((sl << 4) ^ ((row & 7) << 4)));
    *(uint4*)(op + (size_t)row * 64 + sl * 8) = v;
  }
}

extern "C" void kernel_launch(void* const* d_in, const int* in_sizes, int n_in,
                              void* d_out, int out_size, void* d_ws, size_t ws_size,
                              hipStream_t stream) {
  const float* x     = (const float*)d_in[0];
  const float* w_qkv = (const float*)d_in[1];
  const float* w_out = (const float*)d_in[2];
  const float* b_out = (const float*)d_in[3];
  float* out = (float*)d_out;

  const int M = M_ROWS, DIM = 512, NQKV = 1536;

  short* wqkvT = (short*)d_ws;
  short* woutT = wqkvT + (size_t)NQKV * DIM;
  short* qkvb  = woutT + (size_t)DIM * DIM;   // 24 planes [32768][64]
  short* attnb = qkvb + (size_t)M * NQKV;     // 8 planes [32768][64]
  short* xbf   = attnb;  // aliased: xbf dead before attn writes

  transpose_to_bf16<<<(DIM * NQKV + 255) / 256, 256, 0, stream>>>(w_qkv, wqkvT, DIM, NQKV);
  transpose_to_bf16<<<(DIM * DIM + 255) / 256, 256, 0, stream>>>(w_out, woutT, DIM, DIM);
  convert_bf16<<<(M * DIM / 8 + 255) / 256, 256, 0, stream>>>(x, xbf, M * DIM / 8);

  gemm8p_qkv<<<(M / 256) * (NQKV / 256), 512, 0, stream>>>(xbf, wqkvT, qkvb,
                                                           M / 256, NQKV / 256, NQKV);

  attn_kernel<<<1024, 512, 0, stream>>>(qkvb, attnb);

  gemm8p_out<<<(M / 256) * (DIM / 256), 512, 0, stream>>>(attnb, woutT, out, b_out,
                                                          M / 256, DIM / 256, DIM);
}